// Round 6
// baseline (693.626 us; speedup 1.0000x reference)
//
#include <hip/hip_runtime.h>
#include <hip/hip_bf16.h>
#include <cmath>

// Problem constants
constexpr int Bc  = 2;
constexpr int Sc  = 2048;
constexpr int Dc  = 768;
constexpr int Hc  = 12;
constexpr int Ec  = 64;          // d_head
constexpr int BSc = Bc * Sc;     // 4096

typedef _Float16 f16;
typedef __attribute__((ext_vector_type(8)))  _Float16 half8;    // MFMA A/B frag (4 VGPR)
typedef __attribute__((ext_vector_type(16))) float    floatx16; // MFMA C/D (16 VGPR)

typedef __attribute__((address_space(3))) void       lds_void;
typedef __attribute__((address_space(1))) const void glb_cvoid;

// K swizzle: blob per (hb, kt(64), ks(4)), 512 halves: lane(hf*32+col)*8+j =
//   K[hb][key=kt*32+col][e=ks*16+hf*8+j]
// V swizzle: blob per (hb, kt(64), ks2(2), vh(2)), 512 halves: lane*8+j =
//   V[hb][key=kt*32+ks2*16+hf*8+j][e=vh*32+col]   (i.e. V^T fragment order)

// ---------------------------------------------------------------------------
// Kernel 0: prep — x fp32->fp16; W transposes to B-operand [n][k] fp16; bias.
// ---------------------------------------------------------------------------
__global__ __launch_bounds__(256) void prep_kernel(
    const float* __restrict__ x,
    const float* __restrict__ Wq, const float* __restrict__ Wk, const float* __restrict__ Wv,
    const float* __restrict__ bq, const float* __restrict__ bk, const float* __restrict__ bv,
    const float* __restrict__ Wo,
    f16* __restrict__ x16, f16* __restrict__ Wt16, f16* __restrict__ Wot16,
    float* __restrict__ bias_cat)
{
    __shared__ __align__(16) float Ts[64][65];
    const int t = threadIdx.x;
    int bid = blockIdx.x;

    if (bid < 1536) {          // ---- x convert ----
        const size_t base = (size_t)bid * 2048 + t * 8;
        const float4 v0 = *(const float4*)(x + base);
        const float4 v1 = *(const float4*)(x + base + 4);
        half8 hv;
        hv[0] = (f16)v0.x; hv[1] = (f16)v0.y; hv[2] = (f16)v0.z; hv[3] = (f16)v0.w;
        hv[4] = (f16)v1.x; hv[5] = (f16)v1.y; hv[6] = (f16)v1.z; hv[7] = (f16)v1.w;
        *(half8*)(x16 + base) = hv;
        return;
    }
    bid -= 1536;
    if (bid < 432) {           // ---- qkv weight transpose ----
        const int proj = bid / 144, rem = bid % 144, h = rem / 12, dt = rem % 12;
        const float* W = ((proj == 0) ? Wq : (proj == 1) ? Wk : Wv) + (size_t)h * Dc * Ec;
        const int c = t & 63, rr = t >> 6;
        #pragma unroll
        for (int r0 = 0; r0 < 64; r0 += 4) {
            const int d = rr + r0;
            Ts[d][c] = W[(size_t)(dt * 64 + d) * Ec + c];
        }
        __syncthreads();
        #pragma unroll
        for (int r0 = 0; r0 < 64; r0 += 4) {
            const int e = rr + r0;
            Wt16[(size_t)(proj * 768 + h * 64 + e) * Dc + dt * 64 + c] = (f16)Ts[c][e];
        }
        return;
    }
    bid -= 432;
    if (bid < 144) {           // ---- Wo transpose ----
        const int rt = bid / 12, ct = bid % 12;
        const int c = t & 63, rr = t >> 6;
        #pragma unroll
        for (int r0 = 0; r0 < 64; r0 += 4) {
            const int d = rr + r0;
            Ts[d][c] = Wo[(size_t)(rt * 64 + d) * Dc + ct * 64 + c];
        }
        __syncthreads();
        #pragma unroll
        for (int r0 = 0; r0 < 64; r0 += 4) {
            const int e = rr + r0;
            Wot16[(size_t)(ct * 64 + e) * Dc + rt * 64 + c] = (f16)Ts[c][e];
        }
        return;
    }
    bid -= 144;
    {                          // ---- bias concat ----
        const int g = bid * 256 + t;
        if (g < 3 * 768) {
            const int proj = g / 768, idx = g % 768;
            const float* bb = (proj == 0) ? bq : (proj == 1) ? bk : bv;
            bias_cat[g] = bb[idx];
        }
    }
}

// ---------------------------------------------------------------------------
// Kernel 1: QKV GEMM (fp16 MFMA, global_load_lds staging).
// ---------------------------------------------------------------------------
__global__ __launch_bounds__(256, 2) void gemm_qkv_kernel(
    const f16* __restrict__ x16, const f16* __restrict__ Wt16,
    const float* __restrict__ bias_cat,
    f16* __restrict__ q16, f16* __restrict__ kswz, f16* __restrict__ vswz)
{
    __shared__ __align__(16) unsigned char smem[34816];
    f16 (*As)[64]  = (f16(*)[64])smem;              // 128 x 64 = 16384 B
    f16 (*Bs)[64]  = (f16(*)[64])(smem + 16384);    // 128 x 64 = 16384 B
    f16 (*Cs)[136] = (f16(*)[136])smem;             // 128 x 136 = 34816 B (post-loop)

    const int t = threadIdx.x;
    const int wave = t >> 6, lane = t & 63;
    const int col = lane & 31, hf = lane >> 5;
    const int wr = wave & 1, wc = wave >> 1;
    const int m0 = blockIdx.x * 128, n0 = blockIdx.y * 128;
    const int lrow = lane >> 3, lseg = lane & 7;    // staging: 8 lanes per row

    floatx16 c00, c01, c10, c11;
    #pragma unroll
    for (int i = 0; i < 16; ++i) { c00[i] = 0.f; c01[i] = 0.f; c10[i] = 0.f; c11[i] = 0.f; }

    for (int k0 = 0; k0 < Dc; k0 += 64) {
        #pragma unroll
        for (int i = 0; i < 4; ++i) {
            const int r = wave * 32 + i * 8;
            __builtin_amdgcn_global_load_lds(
                (glb_cvoid*)(x16 + (size_t)(m0 + r + lrow) * Dc + k0 + lseg * 8),
                (lds_void*)&As[r][0], 16, 0, 0);
            __builtin_amdgcn_global_load_lds(
                (glb_cvoid*)(Wt16 + (size_t)(n0 + r + lrow) * Dc + k0 + lseg * 8),
                (lds_void*)&Bs[r][0], 16, 0, 0);
        }
        __syncthreads();
        #pragma unroll
        for (int ks = 0; ks < 4; ++ks) {
            const half8 a0 = *(const half8*)&As[wr * 64 + col][ks * 16 + hf * 8];
            const half8 a1 = *(const half8*)&As[wr * 64 + 32 + col][ks * 16 + hf * 8];
            const half8 b0 = *(const half8*)&Bs[wc * 64 + col][ks * 16 + hf * 8];
            const half8 b1 = *(const half8*)&Bs[wc * 64 + 32 + col][ks * 16 + hf * 8];
            c00 = __builtin_amdgcn_mfma_f32_32x32x16_f16(a0, b0, c00, 0, 0, 0);
            c01 = __builtin_amdgcn_mfma_f32_32x32x16_f16(a0, b1, c01, 0, 0, 0);
            c10 = __builtin_amdgcn_mfma_f32_32x32x16_f16(a1, b0, c10, 0, 0, 0);
            c11 = __builtin_amdgcn_mfma_f32_32x32x16_f16(a1, b1, c11, 0, 0, 0);
        }
        __syncthreads();
    }

    const float bias0 = bias_cat[n0 + wc * 64 + col];
    const float bias1 = bias_cat[n0 + wc * 64 + 32 + col];
    #pragma unroll
    for (int i = 0; i < 16; ++i) {
        const int r = (i & 3) + 8 * (i >> 2) + 4 * hf;
        Cs[wr * 64 + r][wc * 64 + col]           = (f16)(c00[i] + bias0);
        Cs[wr * 64 + r][wc * 64 + 32 + col]      = (f16)(c01[i] + bias1);
        Cs[wr * 64 + 32 + r][wc * 64 + col]      = (f16)(c10[i] + bias0);
        Cs[wr * 64 + 32 + r][wc * 64 + 32 + col] = (f16)(c11[i] + bias1);
    }
    __syncthreads();

    const int proj = n0 / 768;
    const int h0   = (n0 - proj * 768) >> 6;   // first of two heads in this tile
    const int b    = m0 >> 11;
    const int s_in = m0 & 2047;
    const int kt0  = s_in >> 5;                // first of 4 key-tiles in m-range

    if (proj == 0) {
        const int row = t >> 1, seg = t & 1;
        const int h = h0 + seg;
        f16* gp = q16 + ((size_t)(h * Bc + b) * Sc + s_in + row) * Ec;
        #pragma unroll
        for (int j = 0; j < 8; ++j)
            *(half8*)(gp + j * 8) = *(const half8*)&Cs[row][seg * 64 + j * 8];
    } else if (proj == 1) {
        #pragma unroll
        for (int ch = 0; ch < 8; ++ch) {
            const int id = ch * 256 + t;            // 0..2047
            const int lane_ = id & 63;
            const int ks  = (id >> 6) & 3;
            const int ktp = (id >> 8) & 3;
            const int seg = (id >> 10) & 1;
            const int colp = lane_ & 31, hfp = lane_ >> 5;
            const int hb = (h0 + seg) * Bc + b;
            const half8 val = *(const half8*)&Cs[ktp * 32 + colp][seg * 64 + ks * 16 + hfp * 8];
            *(half8*)(kswz + ((size_t)((hb * 64 + kt0 + ktp) * 4 + ks) << 9) + lane_ * 8) = val;
        }
    } else {
        #pragma unroll
        for (int ch = 0; ch < 8; ++ch) {
            const int id = ch * 256 + t;
            const int lane_ = id & 63;
            const int ks2 = (id >> 6) & 1;
            const int vh  = (id >> 7) & 1;
            const int ktp = (id >> 8) & 3;
            const int seg = (id >> 10) & 1;
            const int colp = lane_ & 31, hfp = lane_ >> 5;
            const int hb = (h0 + seg) * Bc + b;
            const int e  = vh * 32 + colp;
            half8 val;
            #pragma unroll
            for (int j = 0; j < 8; ++j)
                val[j] = Cs[ktp * 32 + ks2 * 16 + hfp * 8 + j][seg * 64 + e];
            *(half8*)(vswz + ((size_t)(((hb * 64 + kt0 + ktp) * 2 + ks2) * 2 + vh) << 9) + lane_ * 8) = val;
        }
    }
}

// ---------------------------------------------------------------------------
// Kernel 2: fp16 MFMA flash attention, two-pass softmax, swizzled K/V,
// SOFTWARE-PIPELINED loads: V(kt)+mask issue at tile top, K(kt+1) issues
// right after QK(kt) consumes kreg; all loads issue BEFORE the lgkm barrier
// so the memory clobber can't serialize them.
// ---------------------------------------------------------------------------
__global__ __launch_bounds__(256, 3) void flash_attn_kernel(
    const f16* __restrict__ q16, const f16* __restrict__ kswz,
    const f16* __restrict__ vswz, const float* __restrict__ mask,
    f16* __restrict__ obuf16)
{
    __shared__ _Float16 Plds[4][32][40];
    __shared__ float Msh[2][2][32];
    __shared__ float Lsh[2][32];
    __shared__ float OLsh[2][64][33];

    const int rb   = blockIdx.x;
    const int b    = blockIdx.y;
    const int h    = blockIdx.z;
    const int hb   = h * Bc + b;
    const int t    = threadIdx.x;
    const int wave = t >> 6;
    const int lane = t & 63;
    const int rg   = wave & 1;   // row group
    const int kh   = wave >> 1;  // key half
    const int col  = lane & 31;
    const int hf   = lane >> 5;
    const int row0 = rb * 64 + rg * 32;

    const f16* qb  = q16  + ((size_t)hb * Sc + row0) * Ec;
    const f16* kbz = kswz + ((size_t)hb << 17);   // hb * 64*4*512
    const f16* vbz = vswz + ((size_t)hb << 17);   // hb * 64*2*2*512

    half8 qfrag[4];
    #pragma unroll
    for (int ks = 0; ks < 4; ++ks)
        qfrag[ks] = *(const half8*)(qb + (size_t)col * Ec + ks * 16 + hf * 8);

    constexpr int NT = (Sc / 2) / 32;   // 32 tiles per key-half

    // ======== PASS 1: row max (mask <= 0 ⇒ exp(s-mrow) <= 1 stays safe) ====
    float vmax[16];
    #pragma unroll
    for (int i = 0; i < 16; ++i) vmax[i] = -3e38f;

    half8 kreg[4];
    {
        const f16* kp = kbz + ((size_t)(kh * NT) << 11) + lane * 8;
        #pragma unroll
        for (int ks = 0; ks < 4; ++ks) kreg[ks] = *(const half8*)(kp + (ks << 9));
    }
    #pragma unroll 2
    for (int kt = 0; kt < NT; ++kt) {
        floatx16 c;
        #pragma unroll
        for (int i = 0; i < 16; ++i) c[i] = 0.f;
        #pragma unroll
        for (int ks = 0; ks < 4; ++ks)
            c = __builtin_amdgcn_mfma_f32_32x32x16_f16(qfrag[ks], kreg[ks], c, 0, 0, 0);
        if (kt + 1 < NT) {          // prefetch next K tile (hidden behind max)
            const f16* kp = kbz + ((size_t)(kh * NT + kt + 1) << 11) + lane * 8;
            #pragma unroll
            for (int ks = 0; ks < 4; ++ks) kreg[ks] = *(const half8*)(kp + (ks << 9));
        }
        #pragma unroll
        for (int i = 0; i < 16; ++i) vmax[i] = fmaxf(vmax[i], c[i]);
    }
    #pragma unroll
    for (int i = 0; i < 16; ++i) {
        float v = vmax[i];
        v = fmaxf(v, __shfl_xor(v, 1));
        v = fmaxf(v, __shfl_xor(v, 2));
        v = fmaxf(v, __shfl_xor(v, 4));
        v = fmaxf(v, __shfl_xor(v, 8));
        v = fmaxf(v, __shfl_xor(v, 16));
        vmax[i] = v;
    }
    if (col == 0) {
        #pragma unroll
        for (int i = 0; i < 16; ++i) {
            const int r = (i & 3) + 8 * (i >> 2) + 4 * hf;
            Msh[kh][rg][r] = vmax[i];
        }
    }
    __syncthreads();
    float mrow[16];
    #pragma unroll
    for (int i = 0; i < 16; ++i) {
        const int r = (i & 3) + 8 * (i >> 2) + 4 * hf;
        mrow[i] = fmaxf(vmax[i], Msh[1 - kh][rg][r]);
    }

    // ======== PASS 2: exp + PV, no rescaling, pipelined loads ==============
    floatx16 o0, o1;
    float lsum[16];
    #pragma unroll
    for (int i = 0; i < 16; ++i) { o0[i] = 0.f; o1[i] = 0.f; lsum[i] = 0.f; }

    const float* mbase = mask + ((size_t)hb * Sc + row0) * Sc + col;
    const int key_base = kh * (Sc / 2);

    float mbuf[16];
    #pragma unroll
    for (int i = 0; i < 16; ++i) {
        const int r = (i & 3) + 8 * (i >> 2) + 4 * hf;
        mbuf[i] = mbase[(size_t)r * Sc + key_base];
    }
    {   // prefetch K tile 0 of this pass
        const f16* kp = kbz + ((size_t)(kh * NT) << 11) + lane * 8;
        #pragma unroll
        for (int ks = 0; ks < 4; ++ks) kreg[ks] = *(const half8*)(kp + (ks << 9));
    }

    #pragma unroll 2
    for (int kt = 0; kt < NT; ++kt) {
        const int ktg  = kh * NT + kt;
        const int key0 = key_base + kt * 32;

        // V(kt) issue — consumed at tile end (hidden behind QK+exp+LDS)
        const f16* vp = vbz + ((size_t)ktg << 11) + lane * 8;
        const half8 va = *(const half8*)(vp);
        const half8 vb0 = *(const half8*)(vp + (1 << 9));
        const half8 vc = *(const half8*)(vp + (2 << 9));
        const half8 vd = *(const half8*)(vp + (3 << 9));

        // QK on prefetched kreg
        floatx16 c;
        #pragma unroll
        for (int i = 0; i < 16; ++i) c[i] = 0.f;
        #pragma unroll
        for (int ks = 0; ks < 4; ++ks)
            c = __builtin_amdgcn_mfma_f32_32x32x16_f16(qfrag[ks], kreg[ks], c, 0, 0, 0);

        // K(kt+1) issue — hidden behind exp/LDS/PV of this tile
        if (kt + 1 < NT) {
            const f16* kp = kbz + ((size_t)(ktg + 1) << 11) + lane * 8;
            #pragma unroll
            for (int ks = 0; ks < 4; ++ks) kreg[ks] = *(const half8*)(kp + (ks << 9));
        }

        // exp + P write (consumes mbuf)
        #pragma unroll
        for (int i = 0; i < 16; ++i) {
            const float p = __expf(c[i] + mbuf[i] - mrow[i]);   // <= 1: fp16-safe
            lsum[i] += p;
            const int r = (i & 3) + 8 * (i >> 2) + 4 * hf;
            Plds[wave][r][col] = (f16)p;
        }
        // mask(kt+1) issue — consumed next tile (hidden ~1 full tile)
        if (kt + 1 < NT) {
            #pragma unroll
            for (int i = 0; i < 16; ++i) {
                const int r = (i & 3) + 8 * (i >> 2) + 4 * hf;
                mbuf[i] = mbase[(size_t)r * Sc + key0 + 32];
            }
        }
        // same-wave RAW through LDS (per-wave private slice, no block barrier)
        asm volatile("s_waitcnt lgkmcnt(0)" ::: "memory");

        #pragma unroll
        for (int ks2 = 0; ks2 < 2; ++ks2) {
            const half8 pf = *(const half8*)(&Plds[wave][col][ks2 * 16 + hf * 8]);
            const half8 v0 = (ks2 == 0) ? va : vc;
            const half8 v1 = (ks2 == 0) ? vb0 : vd;
            o0 = __builtin_amdgcn_mfma_f32_32x32x16_f16(pf, v0, o0, 0, 0, 0);
            o1 = __builtin_amdgcn_mfma_f32_32x32x16_f16(pf, v1, o1, 0, 0, 0);
        }
    }

    #pragma unroll
    for (int i = 0; i < 16; ++i) {
        float v = lsum[i];
        v += __shfl_xor(v, 1);
        v += __shfl_xor(v, 2);
        v += __shfl_xor(v, 4);
        v += __shfl_xor(v, 8);
        v += __shfl_xor(v, 16);
        lsum[i] = v;
    }

    if (kh == 1) {
        if (col == 0) {
            #pragma unroll
            for (int i = 0; i < 16; ++i) {
                const int r = (i & 3) + 8 * (i >> 2) + 4 * hf;
                Lsh[rg][r] = lsum[i];
            }
        }
        #pragma unroll
        for (int i = 0; i < 16; ++i) {
            OLsh[rg][lane][i]      = o0[i];
            OLsh[rg][lane][16 + i] = o1[i];
        }
    }
    __syncthreads();
    if (kh == 0) {
        #pragma unroll
        for (int i = 0; i < 16; ++i) {
            const int r = (i & 3) + 8 * (i >> 2) + 4 * hf;
            const float inv = 1.f / (lsum[i] + Lsh[rg][r]);
            const float r0 = (o0[i] + OLsh[rg][lane][i])      * inv;
            const float r1 = (o1[i] + OLsh[rg][lane][16 + i]) * inv;
            const size_t orow = ((size_t)b * Sc + row0 + r) * Dc + h * Ec;
            obuf16[orow + col]      = (f16)r0;
            obuf16[orow + 32 + col] = (f16)r1;
        }
    }
}

// ---------------------------------------------------------------------------
// Kernel 3: output GEMM (fp16 MFMA, global_load_lds staging).
// ---------------------------------------------------------------------------
__global__ __launch_bounds__(256, 2) void gemm_out_kernel(
    const f16* __restrict__ a16, const f16* __restrict__ Wot16,
    const float* __restrict__ bo, float* __restrict__ out)
{
    __shared__ __align__(16) f16 As[128][64];
    __shared__ __align__(16) f16 Bs[64][64];

    const int t = threadIdx.x;
    const int wave = t >> 6, lane = t & 63;
    const int col = lane & 31, hf = lane >> 5;
    const int m0 = blockIdx.x * 128, n0 = blockIdx.y * 64;
    const int lrow = lane >> 3, lseg = lane & 7;

    floatx16 c0, c1;
    #pragma unroll
    for (int i = 0; i < 16; ++i) { c0[i] = 0.f; c1[i] = 0.f; }

    for (int k0 = 0; k0 < Dc; k0 += 64) {
        #pragma unroll
        for (int i = 0; i < 4; ++i) {
            const int r = wave * 32 + i * 8;
            __builtin_amdgcn_global_load_lds(
                (glb_cvoid*)(a16 + (size_t)(m0 + r + lrow) * Dc + k0 + lseg * 8),
                (lds_void*)&As[r][0], 16, 0, 0);
        }
        {
            const int r = wave * 16;
            __builtin_amdgcn_global_load_lds(
                (glb_cvoid*)(Wot16 + (size_t)(n0 + r + lrow) * Dc + k0 + lseg * 8),
                (lds_void*)&Bs[r][0], 16, 0, 0);
            __builtin_amdgcn_global_load_lds(
                (glb_cvoid*)(Wot16 + (size_t)(n0 + r + 8 + lrow) * Dc + k0 + lseg * 8),
                (lds_void*)&Bs[r + 8][0], 16, 0, 0);
        }
        __syncthreads();
        #pragma unroll
        for (int ks = 0; ks < 4; ++ks) {
            const half8 a  = *(const half8*)&As[wave * 32 + col][ks * 16 + hf * 8];
            const half8 b0 = *(const half8*)&Bs[col][ks * 16 + hf * 8];
            const half8 b1 = *(const half8*)&Bs[32 + col][ks * 16 + hf * 8];
            c0 = __builtin_amdgcn_mfma_f32_32x32x16_f16(a, b0, c0, 0, 0, 0);
            c1 = __builtin_amdgcn_mfma_f32_32x32x16_f16(a, b1, c1, 0, 0, 0);
        }
        __syncthreads();
    }

    const float bo0 = bo[n0 + col], bo1 = bo[n0 + 32 + col];
    #pragma unroll
    for (int i = 0; i < 16; ++i) {
        const int r = (i & 3) + 8 * (i >> 2) + 4 * hf;
        const size_t ro = (size_t)(m0 + wave * 32 + r) * Dc + n0;
        out[ro + col]      = c0[i] + bo0;
        out[ro + 32 + col] = c1[i] + bo1;
    }
}

// ---------------------------------------------------------------------------
extern "C" void kernel_launch(void* const* d_in, const int* in_sizes, int n_in,
                              void* d_out, int out_size, void* d_ws, size_t ws_size,
                              hipStream_t stream)
{
    const float* x    = (const float*)d_in[0];
    const float* mask = (const float*)d_in[1];
    const float* Wq   = (const float*)d_in[2];
    const float* bq   = (const float*)d_in[3];
    const float* Wk   = (const float*)d_in[4];
    const float* bk   = (const float*)d_in[5];
    const float* Wv   = (const float*)d_in[6];
    const float* bv   = (const float*)d_in[7];
    const float* Wo   = (const float*)d_in[8];
    const float* bo   = (const float*)d_in[9];
    float* out = (float*)d_out;

    constexpr size_t NQ = (size_t)Hc * Bc * Sc * Ec;  // 3,145,728
    f16* x16    = (f16*)d_ws;                      // 4096*768
    f16* Wt16   = x16 + (size_t)BSc * Dc;          // 2304*768
    f16* Wot16  = Wt16 + (size_t)3 * Dc * Dc;      // 768*768
    f16* q16    = Wot16 + (size_t)Dc * Dc;
    f16* kswz   = q16 + NQ;
    f16* vswz   = kswz + NQ;
    f16* obuf16 = vswz + NQ;                       // 4096*768
    float* bias_cat = (float*)(obuf16 + NQ);       // 2304 floats

    prep_kernel<<<2121, 256, 0, stream>>>(x, Wq, Wk, Wv, bq, bk, bv, Wo,
                                          x16, Wt16, Wot16, bias_cat);

    gemm_qkv_kernel<<<dim3(BSc / 128, 2304 / 128), 256, 0, stream>>>(
        x16, Wt16, bias_cat, q16, kswz, vswz);

    flash_attn_kernel<<<dim3(Sc / 64, Bc, Hc), 256, 0, stream>>>(
        q16, kswz, vswz, mask, obuf16);

    gemm_out_kernel<<<dim3(BSc / 128, Dc / 64), 256, 0, stream>>>(
        obuf16, Wot16, bo, out);
}

// Round 7
// 677.921 us; speedup vs baseline: 1.0232x; 1.0232x over previous
//
#include <hip/hip_runtime.h>
#include <hip/hip_bf16.h>
#include <cmath>

// Problem constants
constexpr int Bc  = 2;
constexpr int Sc  = 2048;
constexpr int Dc  = 768;
constexpr int Hc  = 12;
constexpr int Ec  = 64;          // d_head
constexpr int BSc = Bc * Sc;     // 4096

typedef _Float16 f16;
typedef __attribute__((ext_vector_type(8)))  _Float16 half8;    // MFMA A/B frag (4 VGPR)
typedef __attribute__((ext_vector_type(16))) float    floatx16; // MFMA C/D (16 VGPR)

typedef __attribute__((address_space(3))) void       lds_void;
typedef __attribute__((address_space(1))) const void glb_cvoid;

// K swizzle: blob per (hb, kt(64), ks(4)), 512 halves: lane(hf*32+col)*8+j =
//   K[hb][key=kt*32+col][e=ks*16+hf*8+j]
// V swizzle: blob per (hb, kt(64), ks2(2), vh(2)), 512 halves: lane*8+j =
//   V[hb][key=kt*32+ks2*16+hf*8+j][e=vh*32+col]   (i.e. V^T fragment order)

// ---------------------------------------------------------------------------
// Kernel 0: prep — x fp32->fp16; W transposes to B-operand [n][k] fp16; bias.
// ---------------------------------------------------------------------------
__global__ __launch_bounds__(256) void prep_kernel(
    const float* __restrict__ x,
    const float* __restrict__ Wq, const float* __restrict__ Wk, const float* __restrict__ Wv,
    const float* __restrict__ bq, const float* __restrict__ bk, const float* __restrict__ bv,
    const float* __restrict__ Wo,
    f16* __restrict__ x16, f16* __restrict__ Wt16, f16* __restrict__ Wot16,
    float* __restrict__ bias_cat)
{
    __shared__ __align__(16) float Ts[64][65];
    const int t = threadIdx.x;
    int bid = blockIdx.x;

    if (bid < 1536) {          // ---- x convert ----
        const size_t base = (size_t)bid * 2048 + t * 8;
        const float4 v0 = *(const float4*)(x + base);
        const float4 v1 = *(const float4*)(x + base + 4);
        half8 hv;
        hv[0] = (f16)v0.x; hv[1] = (f16)v0.y; hv[2] = (f16)v0.z; hv[3] = (f16)v0.w;
        hv[4] = (f16)v1.x; hv[5] = (f16)v1.y; hv[6] = (f16)v1.z; hv[7] = (f16)v1.w;
        *(half8*)(x16 + base) = hv;
        return;
    }
    bid -= 1536;
    if (bid < 432) {           // ---- qkv weight transpose ----
        const int proj = bid / 144, rem = bid % 144, h = rem / 12, dt = rem % 12;
        const float* W = ((proj == 0) ? Wq : (proj == 1) ? Wk : Wv) + (size_t)h * Dc * Ec;
        const int c = t & 63, rr = t >> 6;
        #pragma unroll
        for (int r0 = 0; r0 < 64; r0 += 4) {
            const int d = rr + r0;
            Ts[d][c] = W[(size_t)(dt * 64 + d) * Ec + c];
        }
        __syncthreads();
        #pragma unroll
        for (int r0 = 0; r0 < 64; r0 += 4) {
            const int e = rr + r0;
            Wt16[(size_t)(proj * 768 + h * 64 + e) * Dc + dt * 64 + c] = (f16)Ts[c][e];
        }
        return;
    }
    bid -= 432;
    if (bid < 144) {           // ---- Wo transpose ----
        const int rt = bid / 12, ct = bid % 12;
        const int c = t & 63, rr = t >> 6;
        #pragma unroll
        for (int r0 = 0; r0 < 64; r0 += 4) {
            const int d = rr + r0;
            Ts[d][c] = Wo[(size_t)(rt * 64 + d) * Dc + ct * 64 + c];
        }
        __syncthreads();
        #pragma unroll
        for (int r0 = 0; r0 < 64; r0 += 4) {
            const int e = rr + r0;
            Wot16[(size_t)(ct * 64 + e) * Dc + rt * 64 + c] = (f16)Ts[c][e];
        }
        return;
    }
    bid -= 144;
    {                          // ---- bias concat ----
        const int g = bid * 256 + t;
        if (g < 3 * 768) {
            const int proj = g / 768, idx = g % 768;
            const float* bb = (proj == 0) ? bq : (proj == 1) ? bk : bv;
            bias_cat[g] = bb[idx];
        }
    }
}

// ---------------------------------------------------------------------------
// Kernel 1: QKV GEMM (fp16 MFMA, global_load_lds staging).
// ---------------------------------------------------------------------------
__global__ __launch_bounds__(256, 2) void gemm_qkv_kernel(
    const f16* __restrict__ x16, const f16* __restrict__ Wt16,
    const float* __restrict__ bias_cat,
    f16* __restrict__ q16, f16* __restrict__ kswz, f16* __restrict__ vswz)
{
    __shared__ __align__(16) unsigned char smem[34816];
    f16 (*As)[64]  = (f16(*)[64])smem;              // 128 x 64 = 16384 B
    f16 (*Bs)[64]  = (f16(*)[64])(smem + 16384);    // 128 x 64 = 16384 B
    f16 (*Cs)[136] = (f16(*)[136])smem;             // 128 x 136 = 34816 B (post-loop)

    const int t = threadIdx.x;
    const int wave = t >> 6, lane = t & 63;
    const int col = lane & 31, hf = lane >> 5;
    const int wr = wave & 1, wc = wave >> 1;
    const int m0 = blockIdx.x * 128, n0 = blockIdx.y * 128;
    const int lrow = lane >> 3, lseg = lane & 7;    // staging: 8 lanes per row

    floatx16 c00, c01, c10, c11;
    #pragma unroll
    for (int i = 0; i < 16; ++i) { c00[i] = 0.f; c01[i] = 0.f; c10[i] = 0.f; c11[i] = 0.f; }

    for (int k0 = 0; k0 < Dc; k0 += 64) {
        #pragma unroll
        for (int i = 0; i < 4; ++i) {
            const int r = wave * 32 + i * 8;
            __builtin_amdgcn_global_load_lds(
                (glb_cvoid*)(x16 + (size_t)(m0 + r + lrow) * Dc + k0 + lseg * 8),
                (lds_void*)&As[r][0], 16, 0, 0);
            __builtin_amdgcn_global_load_lds(
                (glb_cvoid*)(Wt16 + (size_t)(n0 + r + lrow) * Dc + k0 + lseg * 8),
                (lds_void*)&Bs[r][0], 16, 0, 0);
        }
        __syncthreads();
        #pragma unroll
        for (int ks = 0; ks < 4; ++ks) {
            const half8 a0 = *(const half8*)&As[wr * 64 + col][ks * 16 + hf * 8];
            const half8 a1 = *(const half8*)&As[wr * 64 + 32 + col][ks * 16 + hf * 8];
            const half8 b0 = *(const half8*)&Bs[wc * 64 + col][ks * 16 + hf * 8];
            const half8 b1 = *(const half8*)&Bs[wc * 64 + 32 + col][ks * 16 + hf * 8];
            c00 = __builtin_amdgcn_mfma_f32_32x32x16_f16(a0, b0, c00, 0, 0, 0);
            c01 = __builtin_amdgcn_mfma_f32_32x32x16_f16(a0, b1, c01, 0, 0, 0);
            c10 = __builtin_amdgcn_mfma_f32_32x32x16_f16(a1, b0, c10, 0, 0, 0);
            c11 = __builtin_amdgcn_mfma_f32_32x32x16_f16(a1, b1, c11, 0, 0, 0);
        }
        __syncthreads();
    }

    const float bias0 = bias_cat[n0 + wc * 64 + col];
    const float bias1 = bias_cat[n0 + wc * 64 + 32 + col];
    #pragma unroll
    for (int i = 0; i < 16; ++i) {
        const int r = (i & 3) + 8 * (i >> 2) + 4 * hf;
        Cs[wr * 64 + r][wc * 64 + col]           = (f16)(c00[i] + bias0);
        Cs[wr * 64 + r][wc * 64 + 32 + col]      = (f16)(c01[i] + bias1);
        Cs[wr * 64 + 32 + r][wc * 64 + col]      = (f16)(c10[i] + bias0);
        Cs[wr * 64 + 32 + r][wc * 64 + 32 + col] = (f16)(c11[i] + bias1);
    }
    __syncthreads();

    const int proj = n0 / 768;
    const int h0   = (n0 - proj * 768) >> 6;   // first of two heads in this tile
    const int b    = m0 >> 11;
    const int s_in = m0 & 2047;
    const int kt0  = s_in >> 5;                // first of 4 key-tiles in m-range

    if (proj == 0) {
        const int row = t >> 1, seg = t & 1;
        const int h = h0 + seg;
        f16* gp = q16 + ((size_t)(h * Bc + b) * Sc + s_in + row) * Ec;
        #pragma unroll
        for (int j = 0; j < 8; ++j)
            *(half8*)(gp + j * 8) = *(const half8*)&Cs[row][seg * 64 + j * 8];
    } else if (proj == 1) {
        #pragma unroll
        for (int ch = 0; ch < 8; ++ch) {
            const int id = ch * 256 + t;            // 0..2047
            const int lane_ = id & 63;
            const int ks  = (id >> 6) & 3;
            const int ktp = (id >> 8) & 3;
            const int seg = (id >> 10) & 1;
            const int colp = lane_ & 31, hfp = lane_ >> 5;
            const int hb = (h0 + seg) * Bc + b;
            const half8 val = *(const half8*)&Cs[ktp * 32 + colp][seg * 64 + ks * 16 + hfp * 8];
            *(half8*)(kswz + ((size_t)((hb * 64 + kt0 + ktp) * 4 + ks) << 9) + lane_ * 8) = val;
        }
    } else {
        #pragma unroll
        for (int ch = 0; ch < 8; ++ch) {
            const int id = ch * 256 + t;
            const int lane_ = id & 63;
            const int ks2 = (id >> 6) & 1;
            const int vh  = (id >> 7) & 1;
            const int ktp = (id >> 8) & 3;
            const int seg = (id >> 10) & 1;
            const int colp = lane_ & 31, hfp = lane_ >> 5;
            const int hb = (h0 + seg) * Bc + b;
            const int e  = vh * 32 + colp;
            half8 val;
            #pragma unroll
            for (int j = 0; j < 8; ++j)
                val[j] = Cs[ktp * 32 + ks2 * 16 + hfp * 8 + j][seg * 64 + e];
            *(half8*)(vswz + ((size_t)(((hb * 64 + kt0 + ktp) * 2 + ks2) * 2 + vh) << 9) + lane_ * 8) = val;
        }
    }
}

// ---------------------------------------------------------------------------
// Kernel 2: fp16 MFMA flash attention, two-pass softmax, swizzled K/V.
// Mask (the only HBM stream) is register-prefetched FOUR tiles deep
// (window ~1400 cyc > ~900 cyc HBM latency) with non-temporal loads.
// ---------------------------------------------------------------------------
__global__ __launch_bounds__(256, 2) void flash_attn_kernel(
    const f16* __restrict__ q16, const f16* __restrict__ kswz,
    const f16* __restrict__ vswz, const float* __restrict__ mask,
    f16* __restrict__ obuf16)
{
    __shared__ _Float16 Plds[4][32][40];
    __shared__ float Msh[2][2][32];
    __shared__ float Lsh[2][32];
    __shared__ float OLsh[2][64][33];

    const int rb   = blockIdx.x;
    const int b    = blockIdx.y;
    const int h    = blockIdx.z;
    const int hb   = h * Bc + b;
    const int t    = threadIdx.x;
    const int wave = t >> 6;
    const int lane = t & 63;
    const int rg   = wave & 1;   // row group
    const int kh   = wave >> 1;  // key half
    const int col  = lane & 31;
    const int hf   = lane >> 5;
    const int row0 = rb * 64 + rg * 32;

    const f16* qb  = q16  + ((size_t)hb * Sc + row0) * Ec;
    const f16* kbz = kswz + ((size_t)hb << 17);   // hb * 64*4*512
    const f16* vbz = vswz + ((size_t)hb << 17);   // hb * 64*2*2*512

    half8 qfrag[4];
    #pragma unroll
    for (int ks = 0; ks < 4; ++ks)
        qfrag[ks] = *(const half8*)(qb + (size_t)col * Ec + ks * 16 + hf * 8);

    constexpr int NT = (Sc / 2) / 32;   // 32 tiles per key-half

    // ======== PASS 1: row max (mask <= 0 ⇒ exp(s-mrow) <= 1 stays safe) ====
    float vmax[16];
    #pragma unroll
    for (int i = 0; i < 16; ++i) vmax[i] = -3e38f;

    half8 kreg[4];
    {
        const f16* kp = kbz + ((size_t)(kh * NT) << 11) + lane * 8;
        #pragma unroll
        for (int ks = 0; ks < 4; ++ks) kreg[ks] = *(const half8*)(kp + (ks << 9));
    }
    #pragma unroll 2
    for (int kt = 0; kt < NT; ++kt) {
        floatx16 c;
        #pragma unroll
        for (int i = 0; i < 16; ++i) c[i] = 0.f;
        #pragma unroll
        for (int ks = 0; ks < 4; ++ks)
            c = __builtin_amdgcn_mfma_f32_32x32x16_f16(qfrag[ks], kreg[ks], c, 0, 0, 0);
        if (kt + 1 < NT) {          // prefetch next K tile (L2-resident)
            const f16* kp = kbz + ((size_t)(kh * NT + kt + 1) << 11) + lane * 8;
            #pragma unroll
            for (int ks = 0; ks < 4; ++ks) kreg[ks] = *(const half8*)(kp + (ks << 9));
        }
        #pragma unroll
        for (int i = 0; i < 16; ++i) vmax[i] = fmaxf(vmax[i], c[i]);
    }
    #pragma unroll
    for (int i = 0; i < 16; ++i) {
        float v = vmax[i];
        v = fmaxf(v, __shfl_xor(v, 1));
        v = fmaxf(v, __shfl_xor(v, 2));
        v = fmaxf(v, __shfl_xor(v, 4));
        v = fmaxf(v, __shfl_xor(v, 8));
        v = fmaxf(v, __shfl_xor(v, 16));
        vmax[i] = v;
    }
    if (col == 0) {
        #pragma unroll
        for (int i = 0; i < 16; ++i) {
            const int r = (i & 3) + 8 * (i >> 2) + 4 * hf;
            Msh[kh][rg][r] = vmax[i];
        }
    }
    __syncthreads();
    float mrow[16];
    #pragma unroll
    for (int i = 0; i < 16; ++i) {
        const int r = (i & 3) + 8 * (i >> 2) + 4 * hf;
        mrow[i] = fmaxf(vmax[i], Msh[1 - kh][rg][r]);
    }

    // ======== PASS 2: exp + PV, mask prefetched 4 tiles deep ================
    floatx16 o0, o1;
    float lsum[16];
    #pragma unroll
    for (int i = 0; i < 16; ++i) { o0[i] = 0.f; o1[i] = 0.f; lsum[i] = 0.f; }

    const float* mbase = mask + ((size_t)hb * Sc + row0) * Sc + col;
    const int key_base = kh * (Sc / 2);

    float mb[4][16];                // 4-tile-deep mask prefetch ring
    #pragma unroll
    for (int d = 0; d < 4; ++d)
        #pragma unroll
        for (int i = 0; i < 16; ++i) {
            const int r = (i & 3) + 8 * (i >> 2) + 4 * hf;
            mb[d][i] = __builtin_nontemporal_load(
                mbase + (size_t)r * Sc + key_base + d * 32);
        }
    {   // prefetch K tile 0 of this pass
        const f16* kp = kbz + ((size_t)(kh * NT) << 11) + lane * 8;
        #pragma unroll
        for (int ks = 0; ks < 4; ++ks) kreg[ks] = *(const half8*)(kp + (ks << 9));
    }

    for (int kt4 = 0; kt4 < NT; kt4 += 4) {
        #pragma unroll
        for (int s = 0; s < 4; ++s) {
            const int kt  = kt4 + s;
            const int ktg = kh * NT + kt;

            // V(kt) issue — consumed at tile end
            const f16* vp = vbz + ((size_t)ktg << 11) + lane * 8;
            const half8 va  = *(const half8*)(vp);
            const half8 vb0 = *(const half8*)(vp + (1 << 9));
            const half8 vc  = *(const half8*)(vp + (2 << 9));
            const half8 vd  = *(const half8*)(vp + (3 << 9));

            // QK on prefetched kreg
            floatx16 c;
            #pragma unroll
            for (int i = 0; i < 16; ++i) c[i] = 0.f;
            #pragma unroll
            for (int ks = 0; ks < 4; ++ks)
                c = __builtin_amdgcn_mfma_f32_32x32x16_f16(qfrag[ks], kreg[ks], c, 0, 0, 0);

            // K(kt+1) issue
            if (kt + 1 < NT) {
                const f16* kp = kbz + ((size_t)(ktg + 1) << 11) + lane * 8;
                #pragma unroll
                for (int ks = 0; ks < 4; ++ks) kreg[ks] = *(const half8*)(kp + (ks << 9));
            }

            // exp + P write (consumes mb[s], loaded 4 tiles ago)
            #pragma unroll
            for (int i = 0; i < 16; ++i) {
                const float p = __expf(c[i] + mb[s][i] - mrow[i]);   // <= 1
                lsum[i] += p;
                const int r = (i & 3) + 8 * (i >> 2) + 4 * hf;
                Plds[wave][r][col] = (f16)p;
            }
            // mask(kt+4) issue into slot s — 4-tile window
            if (kt4 + s + 4 < NT) {
                #pragma unroll
                for (int i = 0; i < 16; ++i) {
                    const int r = (i & 3) + 8 * (i >> 2) + 4 * hf;
                    mb[s][i] = __builtin_nontemporal_load(
                        mbase + (size_t)r * Sc + key_base + (kt + 4) * 32);
                }
            }
            // same-wave RAW through LDS (per-wave private slice)
            asm volatile("s_waitcnt lgkmcnt(0)" ::: "memory");

            #pragma unroll
            for (int ks2 = 0; ks2 < 2; ++ks2) {
                const half8 pf = *(const half8*)(&Plds[wave][col][ks2 * 16 + hf * 8]);
                const half8 v0 = (ks2 == 0) ? va : vc;
                const half8 v1 = (ks2 == 0) ? vb0 : vd;
                o0 = __builtin_amdgcn_mfma_f32_32x32x16_f16(pf, v0, o0, 0, 0, 0);
                o1 = __builtin_amdgcn_mfma_f32_32x32x16_f16(pf, v1, o1, 0, 0, 0);
            }
        }
    }

    #pragma unroll
    for (int i = 0; i < 16; ++i) {
        float v = lsum[i];
        v += __shfl_xor(v, 1);
        v += __shfl_xor(v, 2);
        v += __shfl_xor(v, 4);
        v += __shfl_xor(v, 8);
        v += __shfl_xor(v, 16);
        lsum[i] = v;
    }

    if (kh == 1) {
        if (col == 0) {
            #pragma unroll
            for (int i = 0; i < 16; ++i) {
                const int r = (i & 3) + 8 * (i >> 2) + 4 * hf;
                Lsh[rg][r] = lsum[i];
            }
        }
        #pragma unroll
        for (int i = 0; i < 16; ++i) {
            OLsh[rg][lane][i]      = o0[i];
            OLsh[rg][lane][16 + i] = o1[i];
        }
    }
    __syncthreads();
    if (kh == 0) {
        #pragma unroll
        for (int i = 0; i < 16; ++i) {
            const int r = (i & 3) + 8 * (i >> 2) + 4 * hf;
            const float inv = 1.f / (lsum[i] + Lsh[rg][r]);
            const float r0 = (o0[i] + OLsh[rg][lane][i])      * inv;
            const float r1 = (o1[i] + OLsh[rg][lane][16 + i]) * inv;
            const size_t orow = ((size_t)b * Sc + row0 + r) * Dc + h * Ec;
            obuf16[orow + col]      = (f16)r0;
            obuf16[orow + 32 + col] = (f16)r1;
        }
    }
}

// ---------------------------------------------------------------------------
// Kernel 3: output GEMM (fp16 MFMA, global_load_lds staging).
// ---------------------------------------------------------------------------
__global__ __launch_bounds__(256, 2) void gemm_out_kernel(
    const f16* __restrict__ a16, const f16* __restrict__ Wot16,
    const float* __restrict__ bo, float* __restrict__ out)
{
    __shared__ __align__(16) f16 As[128][64];
    __shared__ __align__(16) f16 Bs[64][64];

    const int t = threadIdx.x;
    const int wave = t >> 6, lane = t & 63;
    const int col = lane & 31, hf = lane >> 5;
    const int m0 = blockIdx.x * 128, n0 = blockIdx.y * 64;
    const int lrow = lane >> 3, lseg = lane & 7;

    floatx16 c0, c1;
    #pragma unroll
    for (int i = 0; i < 16; ++i) { c0[i] = 0.f; c1[i] = 0.f; }

    for (int k0 = 0; k0 < Dc; k0 += 64) {
        #pragma unroll
        for (int i = 0; i < 4; ++i) {
            const int r = wave * 32 + i * 8;
            __builtin_amdgcn_global_load_lds(
                (glb_cvoid*)(a16 + (size_t)(m0 + r + lrow) * Dc + k0 + lseg * 8),
                (lds_void*)&As[r][0], 16, 0, 0);
        }
        {
            const int r = wave * 16;
            __builtin_amdgcn_global_load_lds(
                (glb_cvoid*)(Wot16 + (size_t)(n0 + r + lrow) * Dc + k0 + lseg * 8),
                (lds_void*)&Bs[r][0], 16, 0, 0);
            __builtin_amdgcn_global_load_lds(
                (glb_cvoid*)(Wot16 + (size_t)(n0 + r + 8 + lrow) * Dc + k0 + lseg * 8),
                (lds_void*)&Bs[r + 8][0], 16, 0, 0);
        }
        __syncthreads();
        #pragma unroll
        for (int ks = 0; ks < 4; ++ks) {
            const half8 a  = *(const half8*)&As[wave * 32 + col][ks * 16 + hf * 8];
            const half8 b0 = *(const half8*)&Bs[col][ks * 16 + hf * 8];
            const half8 b1 = *(const half8*)&Bs[32 + col][ks * 16 + hf * 8];
            c0 = __builtin_amdgcn_mfma_f32_32x32x16_f16(a, b0, c0, 0, 0, 0);
            c1 = __builtin_amdgcn_mfma_f32_32x32x16_f16(a, b1, c1, 0, 0, 0);
        }
        __syncthreads();
    }

    const float bo0 = bo[n0 + col], bo1 = bo[n0 + 32 + col];
    #pragma unroll
    for (int i = 0; i < 16; ++i) {
        const int r = (i & 3) + 8 * (i >> 2) + 4 * hf;
        const size_t ro = (size_t)(m0 + wave * 32 + r) * Dc + n0;
        out[ro + col]      = c0[i] + bo0;
        out[ro + 32 + col] = c1[i] + bo1;
    }
}

// ---------------------------------------------------------------------------
extern "C" void kernel_launch(void* const* d_in, const int* in_sizes, int n_in,
                              void* d_out, int out_size, void* d_ws, size_t ws_size,
                              hipStream_t stream)
{
    const float* x    = (const float*)d_in[0];
    const float* mask = (const float*)d_in[1];
    const float* Wq   = (const float*)d_in[2];
    const float* bq   = (const float*)d_in[3];
    const float* Wk   = (const float*)d_in[4];
    const float* bk   = (const float*)d_in[5];
    const float* Wv   = (const float*)d_in[6];
    const float* bv   = (const float*)d_in[7];
    const float* Wo   = (const float*)d_in[8];
    const float* bo   = (const float*)d_in[9];
    float* out = (float*)d_out;

    constexpr size_t NQ = (size_t)Hc * Bc * Sc * Ec;  // 3,145,728
    f16* x16    = (f16*)d_ws;                      // 4096*768
    f16* Wt16   = x16 + (size_t)BSc * Dc;          // 2304*768
    f16* Wot16  = Wt16 + (size_t)3 * Dc * Dc;      // 768*768
    f16* q16    = Wot16 + (size_t)Dc * Dc;
    f16* kswz   = q16 + NQ;
    f16* vswz   = kswz + NQ;
    f16* obuf16 = vswz + NQ;                       // 4096*768
    float* bias_cat = (float*)(obuf16 + NQ);       // 2304 floats

    prep_kernel<<<2121, 256, 0, stream>>>(x, Wq, Wk, Wv, bq, bk, bv, Wo,
                                          x16, Wt16, Wot16, bias_cat);

    gemm_qkv_kernel<<<dim3(BSc / 128, 2304 / 128), 256, 0, stream>>>(
        x16, Wt16, bias_cat, q16, kswz, vswz);

    flash_attn_kernel<<<dim3(Sc / 64, Bc, Hc), 256, 0, stream>>>(
        q16, kswz, vswz, mask, obuf16);

    gemm_out_kernel<<<dim3(BSc / 128, Dc / 64), 256, 0, stream>>>(
        obuf16, Wot16, bo, out);
}

// Round 9
// 665.260 us; speedup vs baseline: 1.0426x; 1.0190x over previous
//
#include <hip/hip_runtime.h>
#include <hip/hip_bf16.h>
#include <cmath>

// Problem constants
constexpr int Bc  = 2;
constexpr int Sc  = 2048;
constexpr int Dc  = 768;
constexpr int Hc  = 12;
constexpr int Ec  = 64;          // d_head
constexpr int BSc = Bc * Sc;     // 4096

typedef _Float16 f16;
typedef __attribute__((ext_vector_type(8)))  _Float16 half8;    // MFMA A/B frag (4 VGPR)
typedef __attribute__((ext_vector_type(16))) float    floatx16; // MFMA C/D (16 VGPR)
typedef __attribute__((ext_vector_type(4)))  float    fx4;      // clang vec for nontemporal

typedef __attribute__((address_space(3))) void       lds_void;
typedef __attribute__((address_space(1))) const void glb_cvoid;

// K swizzle: blob per (hb, kt(64), ks(4)), 512 halves: lane(hf*32+col)*8+j =
//   K[hb][key=kt*32+col][e=ks*16+hf*8+j]
// V swizzle: blob per (hb, kt(64), ks2(2), vh(2)), 512 halves: lane*8+j =
//   V[hb][key=kt*32+ks2*16+hf*8+j][e=vh*32+col]   (i.e. V^T fragment order)

// ---------------------------------------------------------------------------
// Kernel 0: prep — x fp32->fp16; W transposes to B-operand [n][k] fp16; bias.
// ---------------------------------------------------------------------------
__global__ __launch_bounds__(256) void prep_kernel(
    const float* __restrict__ x,
    const float* __restrict__ Wq, const float* __restrict__ Wk, const float* __restrict__ Wv,
    const float* __restrict__ bq, const float* __restrict__ bk, const float* __restrict__ bv,
    const float* __restrict__ Wo,
    f16* __restrict__ x16, f16* __restrict__ Wt16, f16* __restrict__ Wot16,
    float* __restrict__ bias_cat)
{
    __shared__ __align__(16) float Ts[64][65];
    const int t = threadIdx.x;
    int bid = blockIdx.x;

    if (bid < 1536) {          // ---- x convert ----
        const size_t base = (size_t)bid * 2048 + t * 8;
        const float4 v0 = *(const float4*)(x + base);
        const float4 v1 = *(const float4*)(x + base + 4);
        half8 hv;
        hv[0] = (f16)v0.x; hv[1] = (f16)v0.y; hv[2] = (f16)v0.z; hv[3] = (f16)v0.w;
        hv[4] = (f16)v1.x; hv[5] = (f16)v1.y; hv[6] = (f16)v1.z; hv[7] = (f16)v1.w;
        *(half8*)(x16 + base) = hv;
        return;
    }
    bid -= 1536;
    if (bid < 432) {           // ---- qkv weight transpose ----
        const int proj = bid / 144, rem = bid % 144, h = rem / 12, dt = rem % 12;
        const float* W = ((proj == 0) ? Wq : (proj == 1) ? Wk : Wv) + (size_t)h * Dc * Ec;
        const int c = t & 63, rr = t >> 6;
        #pragma unroll
        for (int r0 = 0; r0 < 64; r0 += 4) {
            const int d = rr + r0;
            Ts[d][c] = W[(size_t)(dt * 64 + d) * Ec + c];
        }
        __syncthreads();
        #pragma unroll
        for (int r0 = 0; r0 < 64; r0 += 4) {
            const int e = rr + r0;
            Wt16[(size_t)(proj * 768 + h * 64 + e) * Dc + dt * 64 + c] = (f16)Ts[c][e];
        }
        return;
    }
    bid -= 432;
    if (bid < 144) {           // ---- Wo transpose ----
        const int rt = bid / 12, ct = bid % 12;
        const int c = t & 63, rr = t >> 6;
        #pragma unroll
        for (int r0 = 0; r0 < 64; r0 += 4) {
            const int d = rr + r0;
            Ts[d][c] = Wo[(size_t)(rt * 64 + d) * Dc + ct * 64 + c];
        }
        __syncthreads();
        #pragma unroll
        for (int r0 = 0; r0 < 64; r0 += 4) {
            const int e = rr + r0;
            Wot16[(size_t)(ct * 64 + e) * Dc + rt * 64 + c] = (f16)Ts[c][e];
        }
        return;
    }
    bid -= 144;
    {                          // ---- bias concat ----
        const int g = bid * 256 + t;
        if (g < 3 * 768) {
            const int proj = g / 768, idx = g % 768;
            const float* bb = (proj == 0) ? bq : (proj == 1) ? bk : bv;
            bias_cat[g] = bb[idx];
        }
    }
}

// ---------------------------------------------------------------------------
// Kernel 1: QKV GEMM (fp16 MFMA, global_load_lds staging).
// ---------------------------------------------------------------------------
__global__ __launch_bounds__(256, 2) void gemm_qkv_kernel(
    const f16* __restrict__ x16, const f16* __restrict__ Wt16,
    const float* __restrict__ bias_cat,
    f16* __restrict__ q16, f16* __restrict__ kswz, f16* __restrict__ vswz)
{
    __shared__ __align__(16) unsigned char smem[34816];
    f16 (*As)[64]  = (f16(*)[64])smem;              // 128 x 64 = 16384 B
    f16 (*Bs)[64]  = (f16(*)[64])(smem + 16384);    // 128 x 64 = 16384 B
    f16 (*Cs)[136] = (f16(*)[136])smem;             // 128 x 136 = 34816 B (post-loop)

    const int t = threadIdx.x;
    const int wave = t >> 6, lane = t & 63;
    const int col = lane & 31, hf = lane >> 5;
    const int wr = wave & 1, wc = wave >> 1;
    const int m0 = blockIdx.x * 128, n0 = blockIdx.y * 128;
    const int lrow = lane >> 3, lseg = lane & 7;    // staging: 8 lanes per row

    floatx16 c00, c01, c10, c11;
    #pragma unroll
    for (int i = 0; i < 16; ++i) { c00[i] = 0.f; c01[i] = 0.f; c10[i] = 0.f; c11[i] = 0.f; }

    for (int k0 = 0; k0 < Dc; k0 += 64) {
        #pragma unroll
        for (int i = 0; i < 4; ++i) {
            const int r = wave * 32 + i * 8;
            __builtin_amdgcn_global_load_lds(
                (glb_cvoid*)(x16 + (size_t)(m0 + r + lrow) * Dc + k0 + lseg * 8),
                (lds_void*)&As[r][0], 16, 0, 0);
            __builtin_amdgcn_global_load_lds(
                (glb_cvoid*)(Wt16 + (size_t)(n0 + r + lrow) * Dc + k0 + lseg * 8),
                (lds_void*)&Bs[r][0], 16, 0, 0);
        }
        __syncthreads();
        #pragma unroll
        for (int ks = 0; ks < 4; ++ks) {
            const half8 a0 = *(const half8*)&As[wr * 64 + col][ks * 16 + hf * 8];
            const half8 a1 = *(const half8*)&As[wr * 64 + 32 + col][ks * 16 + hf * 8];
            const half8 b0 = *(const half8*)&Bs[wc * 64 + col][ks * 16 + hf * 8];
            const half8 b1 = *(const half8*)&Bs[wc * 64 + 32 + col][ks * 16 + hf * 8];
            c00 = __builtin_amdgcn_mfma_f32_32x32x16_f16(a0, b0, c00, 0, 0, 0);
            c01 = __builtin_amdgcn_mfma_f32_32x32x16_f16(a0, b1, c01, 0, 0, 0);
            c10 = __builtin_amdgcn_mfma_f32_32x32x16_f16(a1, b0, c10, 0, 0, 0);
            c11 = __builtin_amdgcn_mfma_f32_32x32x16_f16(a1, b1, c11, 0, 0, 0);
        }
        __syncthreads();
    }

    const float bias0 = bias_cat[n0 + wc * 64 + col];
    const float bias1 = bias_cat[n0 + wc * 64 + 32 + col];
    #pragma unroll
    for (int i = 0; i < 16; ++i) {
        const int r = (i & 3) + 8 * (i >> 2) + 4 * hf;
        Cs[wr * 64 + r][wc * 64 + col]           = (f16)(c00[i] + bias0);
        Cs[wr * 64 + r][wc * 64 + 32 + col]      = (f16)(c01[i] + bias1);
        Cs[wr * 64 + 32 + r][wc * 64 + col]      = (f16)(c10[i] + bias0);
        Cs[wr * 64 + 32 + r][wc * 64 + 32 + col] = (f16)(c11[i] + bias1);
    }
    __syncthreads();

    const int proj = n0 / 768;
    const int h0   = (n0 - proj * 768) >> 6;   // first of two heads in this tile
    const int b    = m0 >> 11;
    const int s_in = m0 & 2047;
    const int kt0  = s_in >> 5;                // first of 4 key-tiles in m-range

    if (proj == 0) {
        const int row = t >> 1, seg = t & 1;
        const int h = h0 + seg;
        f16* gp = q16 + ((size_t)(h * Bc + b) * Sc + s_in + row) * Ec;
        #pragma unroll
        for (int j = 0; j < 8; ++j)
            *(half8*)(gp + j * 8) = *(const half8*)&Cs[row][seg * 64 + j * 8];
    } else if (proj == 1) {
        #pragma unroll
        for (int ch = 0; ch < 8; ++ch) {
            const int id = ch * 256 + t;            // 0..2047
            const int lane_ = id & 63;
            const int ks  = (id >> 6) & 3;
            const int ktp = (id >> 8) & 3;
            const int seg = (id >> 10) & 1;
            const int colp = lane_ & 31, hfp = lane_ >> 5;
            const int hb = (h0 + seg) * Bc + b;
            const half8 val = *(const half8*)&Cs[ktp * 32 + colp][seg * 64 + ks * 16 + hfp * 8];
            *(half8*)(kswz + ((size_t)((hb * 64 + kt0 + ktp) * 4 + ks) << 9) + lane_ * 8) = val;
        }
    } else {
        #pragma unroll
        for (int ch = 0; ch < 8; ++ch) {
            const int id = ch * 256 + t;
            const int lane_ = id & 63;
            const int ks2 = (id >> 6) & 1;
            const int vh  = (id >> 7) & 1;
            const int ktp = (id >> 8) & 3;
            const int seg = (id >> 10) & 1;
            const int colp = lane_ & 31, hfp = lane_ >> 5;
            const int hb = (h0 + seg) * Bc + b;
            const int e  = vh * 32 + colp;
            half8 val;
            #pragma unroll
            for (int j = 0; j < 8; ++j)
                val[j] = Cs[ktp * 32 + ks2 * 16 + hfp * 8 + j][seg * 64 + e];
            *(half8*)(vswz + ((size_t)(((hb * 64 + kt0 + ktp) * 2 + ks2) * 2 + vh) << 9) + lane_ * 8) = val;
        }
    }
}

// ---------------------------------------------------------------------------
// Kernel 2: fp16 MFMA flash attention, two-pass softmax, swizzled K/V.
// Mask loaded with 4x dwordx4 per tile (coalesced) -> wave-private LDS tile ->
// conflict-free ds_read_b32 into C-layout. XCD-swizzled flat grid.
// ---------------------------------------------------------------------------
__global__ __launch_bounds__(256, 3) void flash_attn_kernel(
    const f16* __restrict__ q16, const f16* __restrict__ kswz,
    const f16* __restrict__ vswz, const float* __restrict__ mask,
    f16* __restrict__ obuf16)
{
    // LDS layout (27904 B): Plds 10240 | union{Mall 16384, OLsh 16896} | Msh 512 | Lsh 256
    __shared__ __align__(16) unsigned char shblob[10240 + 16896 + 512 + 256];
    _Float16 (*Plds)[32][40] = (_Float16(*)[32][40])shblob;            // [4][32][40]
    float*    Mall           = (float*)(shblob + 10240);               // [4][32*32]
    float    (*OLsh)[64][33] = (float(*)[64][33])(shblob + 10240);     // overlays Mall
    float    (*Msh)[2][32]   = (float(*)[2][32])(shblob + 10240 + 16896);
    float    (*Lsh)[32]      = (float(*)[32])(shblob + 10240 + 16896 + 512);

    // XCD-aware decode: xcd = f&7 ; 3 (h,b) pairs per XCD -> K/V L2-resident
    const int fblk = blockIdx.x;            // 0..767
    const int kk   = fblk >> 3;             // 0..95
    const int hb   = (fblk & 7) + 8 * (kk >> 5);   // 0..23
    const int rb   = kk & 31;
    const int h    = hb >> 1;
    const int b    = hb & 1;

    const int t    = threadIdx.x;
    const int wave = t >> 6;
    const int lane = t & 63;
    const int rg   = wave & 1;   // row group
    const int kh   = wave >> 1;  // key half
    const int col  = lane & 31;
    const int hf   = lane >> 5;
    const int row0 = rb * 64 + rg * 32;
    const int lrow8 = lane >> 3;           // mask staging: row within 8-row band
    const int lcol4 = (lane & 7) * 4;      // mask staging: key offset

    const f16* qb  = q16  + ((size_t)hb * Sc + row0) * Ec;
    const f16* kbz = kswz + ((size_t)hb << 17);
    const f16* vbz = vswz + ((size_t)hb << 17);

    half8 qfrag[4];
    #pragma unroll
    for (int ks = 0; ks < 4; ++ks)
        qfrag[ks] = *(const half8*)(qb + (size_t)col * Ec + ks * 16 + hf * 8);

    constexpr int NT = (Sc / 2) / 32;   // 32 tiles per key-half

    // ======== PASS 1: row max (mask <= 0 ⇒ exp(s-mrow) <= 1 stays safe) ====
    float vmax[16];
    #pragma unroll
    for (int i = 0; i < 16; ++i) vmax[i] = -3e38f;

    half8 kreg[4];
    {
        const f16* kp = kbz + ((size_t)(kh * NT) << 11) + lane * 8;
        #pragma unroll
        for (int ks = 0; ks < 4; ++ks) kreg[ks] = *(const half8*)(kp + (ks << 9));
    }
    #pragma unroll 2
    for (int kt = 0; kt < NT; ++kt) {
        floatx16 c;
        #pragma unroll
        for (int i = 0; i < 16; ++i) c[i] = 0.f;
        #pragma unroll
        for (int ks = 0; ks < 4; ++ks)
            c = __builtin_amdgcn_mfma_f32_32x32x16_f16(qfrag[ks], kreg[ks], c, 0, 0, 0);
        if (kt + 1 < NT) {
            const f16* kp = kbz + ((size_t)(kh * NT + kt + 1) << 11) + lane * 8;
            #pragma unroll
            for (int ks = 0; ks < 4; ++ks) kreg[ks] = *(const half8*)(kp + (ks << 9));
        }
        #pragma unroll
        for (int i = 0; i < 16; ++i) vmax[i] = fmaxf(vmax[i], c[i]);
    }
    #pragma unroll
    for (int i = 0; i < 16; ++i) {
        float v = vmax[i];
        v = fmaxf(v, __shfl_xor(v, 1));
        v = fmaxf(v, __shfl_xor(v, 2));
        v = fmaxf(v, __shfl_xor(v, 4));
        v = fmaxf(v, __shfl_xor(v, 8));
        v = fmaxf(v, __shfl_xor(v, 16));
        vmax[i] = v;
    }
    if (col == 0) {
        #pragma unroll
        for (int i = 0; i < 16; ++i) {
            const int r = (i & 3) + 8 * (i >> 2) + 4 * hf;
            Msh[kh][rg][r] = vmax[i];
        }
    }
    __syncthreads();
    float mrow[16];
    #pragma unroll
    for (int i = 0; i < 16; ++i) {
        const int r = (i & 3) + 8 * (i >> 2) + 4 * hf;
        mrow[i] = fmaxf(vmax[i], Msh[1 - kh][rg][r]);
    }

    // ======== PASS 2: exp + PV, mask staged through LDS ====================
    floatx16 o0, o1;
    float lsum[16];
    #pragma unroll
    for (int i = 0; i < 16; ++i) { o0[i] = 0.f; o1[i] = 0.f; lsum[i] = 0.f; }

    const float* mw = mask + ((size_t)hb * Sc + row0) * Sc;   // wave's 32-row band
    const int key_base = kh * (Sc / 2);
    float* Mw = Mall + wave * 1024;                            // [32 rows][32 keys]

    fx4 mreg[4];
    // prologue: tile 0 -> LDS; tile 1 -> mreg; K tile 0 -> kreg
    #pragma unroll
    for (int j = 0; j < 4; ++j)
        mreg[j] = __builtin_nontemporal_load(
            (const fx4*)(mw + (size_t)(j * 8 + lrow8) * Sc + key_base + lcol4));
    #pragma unroll
    for (int j = 0; j < 4; ++j)
        *(fx4*)&Mw[(j * 8 + lrow8) * 32 + lcol4] = mreg[j];
    #pragma unroll
    for (int j = 0; j < 4; ++j)
        mreg[j] = __builtin_nontemporal_load(
            (const fx4*)(mw + (size_t)(j * 8 + lrow8) * Sc + key_base + 32 + lcol4));
    {
        const f16* kp = kbz + ((size_t)(kh * NT) << 11) + lane * 8;
        #pragma unroll
        for (int ks = 0; ks < 4; ++ks) kreg[ks] = *(const half8*)(kp + (ks << 9));
    }

    for (int kt = 0; kt < NT; ++kt) {
        const int ktg = kh * NT + kt;

        // V(kt) issue — consumed at tile end
        const f16* vp = vbz + ((size_t)ktg << 11) + lane * 8;
        const half8 va  = *(const half8*)(vp);
        const half8 vb0 = *(const half8*)(vp + (1 << 9));
        const half8 vc  = *(const half8*)(vp + (2 << 9));
        const half8 vd  = *(const half8*)(vp + (3 << 9));

        // QK on prefetched kreg
        floatx16 c;
        #pragma unroll
        for (int i = 0; i < 16; ++i) c[i] = 0.f;
        #pragma unroll
        for (int ks = 0; ks < 4; ++ks)
            c = __builtin_amdgcn_mfma_f32_32x32x16_f16(qfrag[ks], kreg[ks], c, 0, 0, 0);

        // K(kt+1) issue
        if (kt + 1 < NT) {
            const f16* kp = kbz + ((size_t)(ktg + 1) << 11) + lane * 8;
            #pragma unroll
            for (int ks = 0; ks < 4; ++ks) kreg[ks] = *(const half8*)(kp + (ks << 9));
        }

        // mask(kt) from LDS (conflict-free: 2 lanes/bank) + exp + P write
        #pragma unroll
        for (int i = 0; i < 16; ++i) {
            const int r = (i & 3) + 8 * (i >> 2) + 4 * hf;
            const float p = __expf(c[i] + Mw[r * 32 + col] - mrow[i]);   // <= 1
            lsum[i] += p;
            Plds[wave][r][col] = (f16)p;
        }
        // mask(kt+1) regs -> LDS (program order after all Mw reads; DS in-order)
        if (kt + 1 < NT) {
            #pragma unroll
            for (int j = 0; j < 4; ++j)
                *(fx4*)&Mw[(j * 8 + lrow8) * 32 + lcol4] = mreg[j];
        }
        // mask(kt+2) global issue into mreg
        if (kt + 2 < NT) {
            #pragma unroll
            for (int j = 0; j < 4; ++j)
                mreg[j] = __builtin_nontemporal_load(
                    (const fx4*)(mw + (size_t)(j * 8 + lrow8) * Sc
                                 + key_base + (kt + 2) * 32 + lcol4));
        }
        // same-wave RAW through LDS (per-wave private slices)
        asm volatile("s_waitcnt lgkmcnt(0)" ::: "memory");

        #pragma unroll
        for (int ks2 = 0; ks2 < 2; ++ks2) {
            const half8 pf = *(const half8*)(&Plds[wave][col][ks2 * 16 + hf * 8]);
            const half8 v0 = (ks2 == 0) ? va : vc;
            const half8 v1 = (ks2 == 0) ? vb0 : vd;
            o0 = __builtin_amdgcn_mfma_f32_32x32x16_f16(pf, v0, o0, 0, 0, 0);
            o1 = __builtin_amdgcn_mfma_f32_32x32x16_f16(pf, v1, o1, 0, 0, 0);
        }
    }

    #pragma unroll
    for (int i = 0; i < 16; ++i) {
        float v = lsum[i];
        v += __shfl_xor(v, 1);
        v += __shfl_xor(v, 2);
        v += __shfl_xor(v, 4);
        v += __shfl_xor(v, 8);
        v += __shfl_xor(v, 16);
        lsum[i] = v;
    }

    // all waves must be done with Mall before OLsh (aliased) is written
    __syncthreads();
    if (kh == 1) {
        if (col == 0) {
            #pragma unroll
            for (int i = 0; i < 16; ++i) {
                const int r = (i & 3) + 8 * (i >> 2) + 4 * hf;
                Lsh[rg][r] = lsum[i];
            }
        }
        #pragma unroll
        for (int i = 0; i < 16; ++i) {
            OLsh[rg][lane][i]      = o0[i];
            OLsh[rg][lane][16 + i] = o1[i];
        }
    }
    __syncthreads();
    if (kh == 0) {
        #pragma unroll
        for (int i = 0; i < 16; ++i) {
            const int r = (i & 3) + 8 * (i >> 2) + 4 * hf;
            const float inv = 1.f / (lsum[i] + Lsh[rg][r]);
            const float r0 = (o0[i] + OLsh[rg][lane][i])      * inv;
            const float r1 = (o1[i] + OLsh[rg][lane][16 + i]) * inv;
            const size_t orow = ((size_t)b * Sc + row0 + r) * Dc + h * Ec;
            obuf16[orow + col]      = (f16)r0;
            obuf16[orow + 32 + col] = (f16)r1;
        }
    }
}

// ---------------------------------------------------------------------------
// Kernel 3: output GEMM (fp16 MFMA, global_load_lds staging).
// ---------------------------------------------------------------------------
__global__ __launch_bounds__(256, 2) void gemm_out_kernel(
    const f16* __restrict__ a16, const f16* __restrict__ Wot16,
    const float* __restrict__ bo, float* __restrict__ out)
{
    __shared__ __align__(16) f16 As[128][64];
    __shared__ __align__(16) f16 Bs[64][64];

    const int t = threadIdx.x;
    const int wave = t >> 6, lane = t & 63;
    const int col = lane & 31, hf = lane >> 5;
    const int m0 = blockIdx.x * 128, n0 = blockIdx.y * 64;
    const int lrow = lane >> 3, lseg = lane & 7;

    floatx16 c0, c1;
    #pragma unroll
    for (int i = 0; i < 16; ++i) { c0[i] = 0.f; c1[i] = 0.f; }

    for (int k0 = 0; k0 < Dc; k0 += 64) {
        #pragma unroll
        for (int i = 0; i < 4; ++i) {
            const int r = wave * 32 + i * 8;
            __builtin_amdgcn_global_load_lds(
                (glb_cvoid*)(a16 + (size_t)(m0 + r + lrow) * Dc + k0 + lseg * 8),
                (lds_void*)&As[r][0], 16, 0, 0);
        }
        {
            const int r = wave * 16;
            __builtin_amdgcn_global_load_lds(
                (glb_cvoid*)(Wot16 + (size_t)(n0 + r + lrow) * Dc + k0 + lseg * 8),
                (lds_void*)&Bs[r][0], 16, 0, 0);
            __builtin_amdgcn_global_load_lds(
                (glb_cvoid*)(Wot16 + (size_t)(n0 + r + 8 + lrow) * Dc + k0 + lseg * 8),
                (lds_void*)&Bs[r + 8][0], 16, 0, 0);
        }
        __syncthreads();
        #pragma unroll
        for (int ks = 0; ks < 4; ++ks) {
            const half8 a  = *(const half8*)&As[wave * 32 + col][ks * 16 + hf * 8];
            const half8 b0 = *(const half8*)&Bs[col][ks * 16 + hf * 8];
            const half8 b1 = *(const half8*)&Bs[32 + col][ks * 16 + hf * 8];
            c0 = __builtin_amdgcn_mfma_f32_32x32x16_f16(a, b0, c0, 0, 0, 0);
            c1 = __builtin_amdgcn_mfma_f32_32x32x16_f16(a, b1, c1, 0, 0, 0);
        }
        __syncthreads();
    }

    const float bo0 = bo[n0 + col], bo1 = bo[n0 + 32 + col];
    #pragma unroll
    for (int i = 0; i < 16; ++i) {
        const int r = (i & 3) + 8 * (i >> 2) + 4 * hf;
        const size_t ro = (size_t)(m0 + wave * 32 + r) * Dc + n0;
        out[ro + col]      = c0[i] + bo0;
        out[ro + 32 + col] = c1[i] + bo1;
    }
}

// ---------------------------------------------------------------------------
extern "C" void kernel_launch(void* const* d_in, const int* in_sizes, int n_in,
                              void* d_out, int out_size, void* d_ws, size_t ws_size,
                              hipStream_t stream)
{
    const float* x    = (const float*)d_in[0];
    const float* mask = (const float*)d_in[1];
    const float* Wq   = (const float*)d_in[2];
    const float* bq   = (const float*)d_in[3];
    const float* Wk   = (const float*)d_in[4];
    const float* bk   = (const float*)d_in[5];
    const float* Wv   = (const float*)d_in[6];
    const float* bv   = (const float*)d_in[7];
    const float* Wo   = (const float*)d_in[8];
    const float* bo   = (const float*)d_in[9];
    float* out = (float*)d_out;

    constexpr size_t NQ = (size_t)Hc * Bc * Sc * Ec;  // 3,145,728
    f16* x16    = (f16*)d_ws;                      // 4096*768
    f16* Wt16   = x16 + (size_t)BSc * Dc;          // 2304*768
    f16* Wot16  = Wt16 + (size_t)3 * Dc * Dc;      // 768*768
    f16* q16    = Wot16 + (size_t)Dc * Dc;
    f16* kswz   = q16 + NQ;
    f16* vswz   = kswz + NQ;
    f16* obuf16 = vswz + NQ;                       // 4096*768
    float* bias_cat = (float*)(obuf16 + NQ);       // 2304 floats

    prep_kernel<<<2121, 256, 0, stream>>>(x, Wq, Wk, Wv, bq, bk, bv, Wo,
                                          x16, Wt16, Wot16, bias_cat);

    gemm_qkv_kernel<<<dim3(BSc / 128, 2304 / 128), 256, 0, stream>>>(
        x16, Wt16, bias_cat, q16, kswz, vswz);

    flash_attn_kernel<<<768, 256, 0, stream>>>(
        q16, kswz, vswz, mask, obuf16);

    gemm_out_kernel<<<dim3(BSc / 128, Dc / 64), 256, 0, stream>>>(
        obuf16, Wot16, bo, out);
}

// Round 10
// 642.804 us; speedup vs baseline: 1.0791x; 1.0349x over previous
//
#include <hip/hip_runtime.h>
#include <hip/hip_bf16.h>
#include <cmath>

// Problem constants
constexpr int Bc  = 2;
constexpr int Sc  = 2048;
constexpr int Dc  = 768;
constexpr int Hc  = 12;
constexpr int Ec  = 64;          // d_head
constexpr int BSc = Bc * Sc;     // 4096

typedef _Float16 f16;
typedef __attribute__((ext_vector_type(8)))  _Float16 half8;    // MFMA A/B frag (4 VGPR)
typedef __attribute__((ext_vector_type(16))) float    floatx16; // MFMA C/D (16 VGPR)

typedef __attribute__((address_space(3))) void       lds_void;
typedef __attribute__((address_space(1))) const void glb_cvoid;

// K swizzle: blob per (hb, kt(64), ks(4)), 512 halves: lane(hf*32+col)*8+j =
//   K[hb][key=kt*32+col][e=ks*16+hf*8+j]
// V swizzle: blob per (hb, kt(64), ks2(2), vh(2)), 512 halves: lane*8+j =
//   V[hb][key=kt*32+ks2*16+hf*8+j][e=vh*32+col]   (i.e. V^T fragment order)

// ---------------------------------------------------------------------------
// Kernel 0: prep — x fp32->fp16; W transposes to B-operand [n][k] fp16; bias.
// ---------------------------------------------------------------------------
__global__ __launch_bounds__(256) void prep_kernel(
    const float* __restrict__ x,
    const float* __restrict__ Wq, const float* __restrict__ Wk, const float* __restrict__ Wv,
    const float* __restrict__ bq, const float* __restrict__ bk, const float* __restrict__ bv,
    const float* __restrict__ Wo,
    f16* __restrict__ x16, f16* __restrict__ Wt16, f16* __restrict__ Wot16,
    float* __restrict__ bias_cat)
{
    __shared__ __align__(16) float Ts[64][65];
    const int t = threadIdx.x;
    int bid = blockIdx.x;

    if (bid < 1536) {          // ---- x convert ----
        const size_t base = (size_t)bid * 2048 + t * 8;
        const float4 v0 = *(const float4*)(x + base);
        const float4 v1 = *(const float4*)(x + base + 4);
        half8 hv;
        hv[0] = (f16)v0.x; hv[1] = (f16)v0.y; hv[2] = (f16)v0.z; hv[3] = (f16)v0.w;
        hv[4] = (f16)v1.x; hv[5] = (f16)v1.y; hv[6] = (f16)v1.z; hv[7] = (f16)v1.w;
        *(half8*)(x16 + base) = hv;
        return;
    }
    bid -= 1536;
    if (bid < 432) {           // ---- qkv weight transpose ----
        const int proj = bid / 144, rem = bid % 144, h = rem / 12, dt = rem % 12;
        const float* W = ((proj == 0) ? Wq : (proj == 1) ? Wk : Wv) + (size_t)h * Dc * Ec;
        const int c = t & 63, rr = t >> 6;
        #pragma unroll
        for (int r0 = 0; r0 < 64; r0 += 4) {
            const int d = rr + r0;
            Ts[d][c] = W[(size_t)(dt * 64 + d) * Ec + c];
        }
        __syncthreads();
        #pragma unroll
        for (int r0 = 0; r0 < 64; r0 += 4) {
            const int e = rr + r0;
            Wt16[(size_t)(proj * 768 + h * 64 + e) * Dc + dt * 64 + c] = (f16)Ts[c][e];
        }
        return;
    }
    bid -= 432;
    if (bid < 144) {           // ---- Wo transpose ----
        const int rt = bid / 12, ct = bid % 12;
        const int c = t & 63, rr = t >> 6;
        #pragma unroll
        for (int r0 = 0; r0 < 64; r0 += 4) {
            const int d = rr + r0;
            Ts[d][c] = Wo[(size_t)(rt * 64 + d) * Dc + ct * 64 + c];
        }
        __syncthreads();
        #pragma unroll
        for (int r0 = 0; r0 < 64; r0 += 4) {
            const int e = rr + r0;
            Wot16[(size_t)(ct * 64 + e) * Dc + rt * 64 + c] = (f16)Ts[c][e];
        }
        return;
    }
    bid -= 144;
    {                          // ---- bias concat ----
        const int g = bid * 256 + t;
        if (g < 3 * 768) {
            const int proj = g / 768, idx = g % 768;
            const float* bb = (proj == 0) ? bq : (proj == 1) ? bk : bv;
            bias_cat[g] = bb[idx];
        }
    }
}

// ---------------------------------------------------------------------------
// Kernel 1: QKV GEMM (fp16 MFMA, global_load_lds staging).
// ---------------------------------------------------------------------------
__global__ __launch_bounds__(256, 2) void gemm_qkv_kernel(
    const f16* __restrict__ x16, const f16* __restrict__ Wt16,
    const float* __restrict__ bias_cat,
    f16* __restrict__ q16, f16* __restrict__ kswz, f16* __restrict__ vswz)
{
    __shared__ __align__(16) unsigned char smem[34816];
    f16 (*As)[64]  = (f16(*)[64])smem;              // 128 x 64 = 16384 B
    f16 (*Bs)[64]  = (f16(*)[64])(smem + 16384);    // 128 x 64 = 16384 B
    f16 (*Cs)[136] = (f16(*)[136])smem;             // 128 x 136 = 34816 B (post-loop)

    const int t = threadIdx.x;
    const int wave = t >> 6, lane = t & 63;
    const int col = lane & 31, hf = lane >> 5;
    const int wr = wave & 1, wc = wave >> 1;
    const int m0 = blockIdx.x * 128, n0 = blockIdx.y * 128;
    const int lrow = lane >> 3, lseg = lane & 7;    // staging: 8 lanes per row

    floatx16 c00, c01, c10, c11;
    #pragma unroll
    for (int i = 0; i < 16; ++i) { c00[i] = 0.f; c01[i] = 0.f; c10[i] = 0.f; c11[i] = 0.f; }

    for (int k0 = 0; k0 < Dc; k0 += 64) {
        #pragma unroll
        for (int i = 0; i < 4; ++i) {
            const int r = wave * 32 + i * 8;
            __builtin_amdgcn_global_load_lds(
                (glb_cvoid*)(x16 + (size_t)(m0 + r + lrow) * Dc + k0 + lseg * 8),
                (lds_void*)&As[r][0], 16, 0, 0);
            __builtin_amdgcn_global_load_lds(
                (glb_cvoid*)(Wt16 + (size_t)(n0 + r + lrow) * Dc + k0 + lseg * 8),
                (lds_void*)&Bs[r][0], 16, 0, 0);
        }
        __syncthreads();
        #pragma unroll
        for (int ks = 0; ks < 4; ++ks) {
            const half8 a0 = *(const half8*)&As[wr * 64 + col][ks * 16 + hf * 8];
            const half8 a1 = *(const half8*)&As[wr * 64 + 32 + col][ks * 16 + hf * 8];
            const half8 b0 = *(const half8*)&Bs[wc * 64 + col][ks * 16 + hf * 8];
            const half8 b1 = *(const half8*)&Bs[wc * 64 + 32 + col][ks * 16 + hf * 8];
            c00 = __builtin_amdgcn_mfma_f32_32x32x16_f16(a0, b0, c00, 0, 0, 0);
            c01 = __builtin_amdgcn_mfma_f32_32x32x16_f16(a0, b1, c01, 0, 0, 0);
            c10 = __builtin_amdgcn_mfma_f32_32x32x16_f16(a1, b0, c10, 0, 0, 0);
            c11 = __builtin_amdgcn_mfma_f32_32x32x16_f16(a1, b1, c11, 0, 0, 0);
        }
        __syncthreads();
    }

    const float bias0 = bias_cat[n0 + wc * 64 + col];
    const float bias1 = bias_cat[n0 + wc * 64 + 32 + col];
    #pragma unroll
    for (int i = 0; i < 16; ++i) {
        const int r = (i & 3) + 8 * (i >> 2) + 4 * hf;
        Cs[wr * 64 + r][wc * 64 + col]           = (f16)(c00[i] + bias0);
        Cs[wr * 64 + r][wc * 64 + 32 + col]      = (f16)(c01[i] + bias1);
        Cs[wr * 64 + 32 + r][wc * 64 + col]      = (f16)(c10[i] + bias0);
        Cs[wr * 64 + 32 + r][wc * 64 + 32 + col] = (f16)(c11[i] + bias1);
    }
    __syncthreads();

    const int proj = n0 / 768;
    const int h0   = (n0 - proj * 768) >> 6;   // first of two heads in this tile
    const int b    = m0 >> 11;
    const int s_in = m0 & 2047;
    const int kt0  = s_in >> 5;                // first of 4 key-tiles in m-range

    if (proj == 0) {
        const int row = t >> 1, seg = t & 1;
        const int h = h0 + seg;
        f16* gp = q16 + ((size_t)(h * Bc + b) * Sc + s_in + row) * Ec;
        #pragma unroll
        for (int j = 0; j < 8; ++j)
            *(half8*)(gp + j * 8) = *(const half8*)&Cs[row][seg * 64 + j * 8];
    } else if (proj == 1) {
        #pragma unroll
        for (int ch = 0; ch < 8; ++ch) {
            const int id = ch * 256 + t;            // 0..2047
            const int lane_ = id & 63;
            const int ks  = (id >> 6) & 3;
            const int ktp = (id >> 8) & 3;
            const int seg = (id >> 10) & 1;
            const int colp = lane_ & 31, hfp = lane_ >> 5;
            const int hb = (h0 + seg) * Bc + b;
            const half8 val = *(const half8*)&Cs[ktp * 32 + colp][seg * 64 + ks * 16 + hfp * 8];
            *(half8*)(kswz + ((size_t)((hb * 64 + kt0 + ktp) * 4 + ks) << 9) + lane_ * 8) = val;
        }
    } else {
        #pragma unroll
        for (int ch = 0; ch < 8; ++ch) {
            const int id = ch * 256 + t;
            const int lane_ = id & 63;
            const int ks2 = (id >> 6) & 1;
            const int vh  = (id >> 7) & 1;
            const int ktp = (id >> 8) & 3;
            const int seg = (id >> 10) & 1;
            const int colp = lane_ & 31, hfp = lane_ >> 5;
            const int hb = (h0 + seg) * Bc + b;
            const int e  = vh * 32 + colp;
            half8 val;
            #pragma unroll
            for (int j = 0; j < 8; ++j)
                val[j] = Cs[ktp * 32 + ks2 * 16 + hfp * 8 + j][seg * 64 + e];
            *(half8*)(vswz + ((size_t)(((hb * 64 + kt0 + ktp) * 2 + ks2) * 2 + vh) << 9) + lane_ * 8) = val;
        }
    }
}

// ---------------------------------------------------------------------------
// Kernel 2: fp16 MFMA flash attention. 128 threads = 2 waves; each wave owns
// 32 query rows and sweeps ALL 2048 keys (no key-half split, no combine).
// Mask staged per-block as 64x128 fp32 mega-tiles (32 KB) via global_load_lds
// dwordx4 — bulk 512 B/row page-friendly DMA instead of 128 B/row scatter.
// Two-pass softmax: pass 1 row max (intra-wave only), pass 2 exp+PV.
// ---------------------------------------------------------------------------
__global__ __launch_bounds__(128, 2) void flash_attn_kernel(
    const f16* __restrict__ q16, const f16* __restrict__ kswz,
    const f16* __restrict__ vswz, const float* __restrict__ mask,
    f16* __restrict__ obuf16)
{
    __shared__ __align__(16) float Mall[64 * 128];   // 32 KB mask mega-tile
    __shared__ _Float16 Plds[2][32][40];             // 5 KB per-wave P tiles

    // XCD-aware decode: xcd = fblk&7 ; 3 hb per XCD -> K/V L2-resident
    const int fblk = blockIdx.x;            // 0..767
    const int kk   = fblk >> 3;             // 0..95
    const int hb   = (fblk & 7) + 8 * (kk >> 5);   // 0..23
    const int rb   = kk & 31;
    const int h    = hb >> 1;
    const int b    = hb & 1;

    const int t    = threadIdx.x;
    const int wave = t >> 6;     // row group (0/1)
    const int lane = t & 63;
    const int col  = lane & 31;
    const int hf   = lane >> 5;
    const int row0 = rb * 64 + wave * 32;

    const f16* qb  = q16  + ((size_t)hb * Sc + row0) * Ec;
    const f16* kbz = kswz + ((size_t)hb << 17);
    const f16* vbz = vswz + ((size_t)hb << 17);
    const float* mband = mask + ((size_t)hb * Sc + rb * 64) * Sc;  // block's 64-row band

    half8 qfrag[4];
    #pragma unroll
    for (int ks = 0; ks < 4; ++ks)
        qfrag[ks] = *(const half8*)(qb + (size_t)col * Ec + ks * 16 + hf * 8);

    constexpr int NT = Sc / 32;   // 64 key tiles

    // ======== PASS 1: row max (mask <= 0 ⇒ exp(s-mrow) <= 1 stays safe) ====
    float vmax[16];
    #pragma unroll
    for (int i = 0; i < 16; ++i) vmax[i] = -3e38f;

    half8 kreg[4];
    {
        const f16* kp = kbz + lane * 8;
        #pragma unroll
        for (int ks = 0; ks < 4; ++ks) kreg[ks] = *(const half8*)(kp + (ks << 9));
    }
    #pragma unroll 2
    for (int kt = 0; kt < NT; ++kt) {
        floatx16 c;
        #pragma unroll
        for (int i = 0; i < 16; ++i) c[i] = 0.f;
        #pragma unroll
        for (int ks = 0; ks < 4; ++ks)
            c = __builtin_amdgcn_mfma_f32_32x32x16_f16(qfrag[ks], kreg[ks], c, 0, 0, 0);
        if (kt + 1 < NT) {
            const f16* kp = kbz + ((size_t)(kt + 1) << 11) + lane * 8;
            #pragma unroll
            for (int ks = 0; ks < 4; ++ks) kreg[ks] = *(const half8*)(kp + (ks << 9));
        }
        #pragma unroll
        for (int i = 0; i < 16; ++i) vmax[i] = fmaxf(vmax[i], c[i]);
    }
    float mrow[16];
    #pragma unroll
    for (int i = 0; i < 16; ++i) {
        float v = vmax[i];
        v = fmaxf(v, __shfl_xor(v, 1));
        v = fmaxf(v, __shfl_xor(v, 2));
        v = fmaxf(v, __shfl_xor(v, 4));
        v = fmaxf(v, __shfl_xor(v, 8));
        v = fmaxf(v, __shfl_xor(v, 16));
        mrow[i] = v;
    }

    // ======== PASS 2: exp + PV; mask staged 4 tiles at a time ==============
    floatx16 o0, o1;
    float lsum[16];
    #pragma unroll
    for (int i = 0; i < 16; ++i) { o0[i] = 0.f; o1[i] = 0.f; lsum[i] = 0.f; }

    {   // K tile 0 prefetch
        const f16* kp = kbz + lane * 8;
        #pragma unroll
        for (int ks = 0; ks < 4; ++ks) kreg[ks] = *(const half8*)(kp + (ks << 9));
    }

    for (int rd = 0; rd < NT / 4; ++rd) {           // 16 rounds of 4 key-tiles
        __syncthreads();                            // prev round's Mall reads done
        // stage 64 rows x 128 keys: wave stages its own 32 rows, 2 rows/inst
        #pragma unroll
        for (int j = 0; j < 16; ++j) {
            const int row = wave * 32 + 2 * j;      // +lane>>5 row pair by HW lanes
            __builtin_amdgcn_global_load_lds(
                (glb_cvoid*)(mband + (size_t)(row + (lane >> 5)) * Sc
                             + rd * 128 + (lane & 31) * 4),
                (lds_void*)&Mall[row * 128], 16, 0, 0);
        }
        __syncthreads();                            // drains vmcnt -> staged visible

        #pragma unroll
        for (int s = 0; s < 4; ++s) {
            const int kt = rd * 4 + s;

            // V(kt) issue — consumed at tile end
            const f16* vp = vbz + ((size_t)kt << 11) + lane * 8;
            const half8 va  = *(const half8*)(vp);
            const half8 vb0 = *(const half8*)(vp + (1 << 9));
            const half8 vc  = *(const half8*)(vp + (2 << 9));
            const half8 vd  = *(const half8*)(vp + (3 << 9));

            // QK on prefetched kreg
            floatx16 c;
            #pragma unroll
            for (int i = 0; i < 16; ++i) c[i] = 0.f;
            #pragma unroll
            for (int ks = 0; ks < 4; ++ks)
                c = __builtin_amdgcn_mfma_f32_32x32x16_f16(qfrag[ks], kreg[ks], c, 0, 0, 0);

            // K(kt+1) issue
            if (kt + 1 < NT) {
                const f16* kp = kbz + ((size_t)(kt + 1) << 11) + lane * 8;
                #pragma unroll
                for (int ks = 0; ks < 4; ++ks) kreg[ks] = *(const half8*)(kp + (ks << 9));
            }

            // mask from LDS (2 lanes/bank = free) + exp + P write
            #pragma unroll
            for (int i = 0; i < 16; ++i) {
                const int r = (i & 3) + 8 * (i >> 2) + 4 * hf;
                const float m = Mall[(wave * 32 + r) * 128 + s * 32 + col];
                const float p = __expf(c[i] + m - mrow[i]);   // <= 1: fp16-safe
                lsum[i] += p;
                Plds[wave][r][col] = (f16)p;
            }
            // same-wave RAW through LDS (per-wave private slice)
            asm volatile("s_waitcnt lgkmcnt(0)" ::: "memory");

            #pragma unroll
            for (int ks2 = 0; ks2 < 2; ++ks2) {
                const half8 pf = *(const half8*)(&Plds[wave][col][ks2 * 16 + hf * 8]);
                const half8 v0 = (ks2 == 0) ? va : vc;
                const half8 v1 = (ks2 == 0) ? vb0 : vd;
                o0 = __builtin_amdgcn_mfma_f32_32x32x16_f16(pf, v0, o0, 0, 0, 0);
                o1 = __builtin_amdgcn_mfma_f32_32x32x16_f16(pf, v1, o1, 0, 0, 0);
            }
        }
    }

    // final l reduction + normalize + store (no cross-wave combine needed)
    #pragma unroll
    for (int i = 0; i < 16; ++i) {
        float v = lsum[i];
        v += __shfl_xor(v, 1);
        v += __shfl_xor(v, 2);
        v += __shfl_xor(v, 4);
        v += __shfl_xor(v, 8);
        v += __shfl_xor(v, 16);
        const float inv = 1.f / v;
        const int r = (i & 3) + 8 * (i >> 2) + 4 * hf;
        const size_t orow = ((size_t)b * Sc + row0 + r) * Dc + h * Ec;
        obuf16[orow + col]      = (f16)(o0[i] * inv);
        obuf16[orow + 32 + col] = (f16)(o1[i] * inv);
    }
}

// ---------------------------------------------------------------------------
// Kernel 3: output GEMM (fp16 MFMA, global_load_lds staging).
// ---------------------------------------------------------------------------
__global__ __launch_bounds__(256, 2) void gemm_out_kernel(
    const f16* __restrict__ a16, const f16* __restrict__ Wot16,
    const float* __restrict__ bo, float* __restrict__ out)
{
    __shared__ __align__(16) f16 As[128][64];
    __shared__ __align__(16) f16 Bs[64][64];

    const int t = threadIdx.x;
    const int wave = t >> 6, lane = t & 63;
    const int col = lane & 31, hf = lane >> 5;
    const int m0 = blockIdx.x * 128, n0 = blockIdx.y * 64;
    const int lrow = lane >> 3, lseg = lane & 7;

    floatx16 c0, c1;
    #pragma unroll
    for (int i = 0; i < 16; ++i) { c0[i] = 0.f; c1[i] = 0.f; }

    for (int k0 = 0; k0 < Dc; k0 += 64) {
        #pragma unroll
        for (int i = 0; i < 4; ++i) {
            const int r = wave * 32 + i * 8;
            __builtin_amdgcn_global_load_lds(
                (glb_cvoid*)(a16 + (size_t)(m0 + r + lrow) * Dc + k0 + lseg * 8),
                (lds_void*)&As[r][0], 16, 0, 0);
        }
        {
            const int r = wave * 16;
            __builtin_amdgcn_global_load_lds(
                (glb_cvoid*)(Wot16 + (size_t)(n0 + r + lrow) * Dc + k0 + lseg * 8),
                (lds_void*)&Bs[r][0], 16, 0, 0);
            __builtin_amdgcn_global_load_lds(
                (glb_cvoid*)(Wot16 + (size_t)(n0 + r + 8 + lrow) * Dc + k0 + lseg * 8),
                (lds_void*)&Bs[r + 8][0], 16, 0, 0);
        }
        __syncthreads();
        #pragma unroll
        for (int ks = 0; ks < 4; ++ks) {
            const half8 a  = *(const half8*)&As[wave * 32 + col][ks * 16 + hf * 8];
            const half8 b0 = *(const half8*)&Bs[col][ks * 16 + hf * 8];
            const half8 b1 = *(const half8*)&Bs[32 + col][ks * 16 + hf * 8];
            c0 = __builtin_amdgcn_mfma_f32_32x32x16_f16(a, b0, c0, 0, 0, 0);
            c1 = __builtin_amdgcn_mfma_f32_32x32x16_f16(a, b1, c1, 0, 0, 0);
        }
        __syncthreads();
    }

    const float bo0 = bo[n0 + col], bo1 = bo[n0 + 32 + col];
    #pragma unroll
    for (int i = 0; i < 16; ++i) {
        const int r = (i & 3) + 8 * (i >> 2) + 4 * hf;
        const size_t ro = (size_t)(m0 + wave * 32 + r) * Dc + n0;
        out[ro + col]      = c0[i] + bo0;
        out[ro + 32 + col] = c1[i] + bo1;
    }
}

// ---------------------------------------------------------------------------
extern "C" void kernel_launch(void* const* d_in, const int* in_sizes, int n_in,
                              void* d_out, int out_size, void* d_ws, size_t ws_size,
                              hipStream_t stream)
{
    const float* x    = (const float*)d_in[0];
    const float* mask = (const float*)d_in[1];
    const float* Wq   = (const float*)d_in[2];
    const float* bq   = (const float*)d_in[3];
    const float* Wk   = (const float*)d_in[4];
    const float* bk   = (const float*)d_in[5];
    const float* Wv   = (const float*)d_in[6];
    const float* bv   = (const float*)d_in[7];
    const float* Wo   = (const float*)d_in[8];
    const float* bo   = (const float*)d_in[9];
    float* out = (float*)d_out;

    constexpr size_t NQ = (size_t)Hc * Bc * Sc * Ec;  // 3,145,728
    f16* x16    = (f16*)d_ws;                      // 4096*768
    f16* Wt16   = x16 + (size_t)BSc * Dc;          // 2304*768
    f16* Wot16  = Wt16 + (size_t)3 * Dc * Dc;      // 768*768
    f16* q16    = Wot16 + (size_t)Dc * Dc;
    f16* kswz   = q16 + NQ;
    f16* vswz   = kswz + NQ;
    f16* obuf16 = vswz + NQ;                       // 4096*768
    float* bias_cat = (float*)(obuf16 + NQ);       // 2304 floats

    prep_kernel<<<2121, 256, 0, stream>>>(x, Wq, Wk, Wv, bq, bk, bv, Wo,
                                          x16, Wt16, Wot16, bias_cat);

    gemm_qkv_kernel<<<dim3(BSc / 128, 2304 / 128), 256, 0, stream>>>(
        x16, Wt16, bias_cat, q16, kswz, vswz);

    flash_attn_kernel<<<768, 128, 0, stream>>>(
        q16, kswz, vswz, mask, obuf16);

    gemm_out_kernel<<<dim3(BSc / 128, Dc / 64), 256, 0, stream>>>(
        obuf16, Wot16, bo, out);
}